// Round 1
// baseline (2017.925 us; speedup 1.0000x reference)
//
#include <hip/hip_runtime.h>
#include <hip/hip_bf16.h>
#include <stdio.h>

#define DIM 2048
#define HID 2730
#define HID_PAD 2816   // 22*128, zero-padded
#define NE 8
#define NTOK 8192      // B*T
#define NROWS 24576    // 16384 expert-assignment rows + 8192 shared rows

typedef __bf16 v8bf __attribute__((ext_vector_type(8)));
typedef float v4f  __attribute__((ext_vector_type(4)));

// async global->LDS, 16B per lane, wave-uniform LDS base + lane*16 (m97/m104 semantics)
__device__ __forceinline__ void gload16(const void* g, void* l){
  __builtin_amdgcn_global_load_lds((const __attribute__((address_space(1))) void*)g,
                                   (__attribute__((address_space(3))) void*)l, 16, 0, 0);
}

// ---------------- small utility kernels ----------------

__global__ void moe_zero_i(int* __restrict__ p, int n){
  int i = threadIdx.x;
  if (i < n) p[i] = 0;
}

__global__ void moe_cast_x(const float* __restrict__ x, __hip_bfloat16* __restrict__ xb){
  int i = (blockIdx.x*blockDim.x + threadIdx.x)*4;
  float4 v = *reinterpret_cast<const float4*>(x + i);
  __hip_bfloat16 o[4];
  o[0]=__float2bfloat16(v.x); o[1]=__float2bfloat16(v.y);
  o[2]=__float2bfloat16(v.z); o[3]=__float2bfloat16(v.w);
  unsigned long long u; __builtin_memcpy(&u, o, 8);
  *reinterpret_cast<unsigned long long*>(xb + i) = u;
}

// transpose-cast fp32 -> bf16, B^T layout with zero padding.
__global__ void moe_tcast(const float* __restrict__ srcE, const float* __restrict__ srcS,
                          __hip_bfloat16* __restrict__ dst, int R, int C, int Cp, int Rp){
  int e = blockIdx.z;
  const float* src = (e < NE) ? (srcE + (size_t)e*R*C) : srcS;
  __hip_bfloat16* d = dst + (size_t)e*Cp*Rp;
  __shared__ float tile[32][33];
  int c0 = blockIdx.x*32, r0 = blockIdx.y*32;
  #pragma unroll
  for (int i=0;i<4;i++){
    int r = r0 + threadIdx.y + i*8, c = c0 + threadIdx.x;
    float v = (r < R && c < C) ? src[(size_t)r*C + c] : 0.0f;
    tile[threadIdx.y + i*8][threadIdx.x] = v;
  }
  __syncthreads();
  #pragma unroll
  for (int i=0;i<4;i++){
    int c = c0 + threadIdx.y + i*8, r = r0 + threadIdx.x;
    if (c < Cp && r < Rp)
      d[(size_t)c*Rp + r] = __float2bfloat16(tile[threadIdx.x][threadIdx.y + i*8]);
  }
}

// ---------------- router: fp32 logits, softmax, top-2, bucket ----------------

__global__ __launch_bounds__(256) void moe_router(
    const float* __restrict__ x, const float* __restrict__ rw,
    float* __restrict__ topw, int* __restrict__ cnt, int* __restrict__ bucket){
  int wav = threadIdx.x >> 6, lane = threadIdx.x & 63;
  int t = blockIdx.x*4 + wav;
  const float* xr = x + (size_t)t*DIM;
  float a[NE];
  #pragma unroll
  for (int e=0;e<NE;e++) a[e]=0.f;
  for (int d0 = lane; d0 < DIM; d0 += 64){
    float xv = xr[d0];
    const float* rr = rw + d0*NE;
    #pragma unroll
    for (int e=0;e<NE;e++) a[e] += xv * rr[e];
  }
  #pragma unroll
  for (int e=0;e<NE;e++){
    float v = a[e];
    #pragma unroll
    for (int o=32;o>0;o>>=1) v += __shfl_xor(v, o);
    a[e]=v;
  }
  if (lane == 0){
    float m = a[0];
    for (int e=1;e<NE;e++) m = fmaxf(m, a[e]);
    float p[NE];
    for (int e=0;e<NE;e++) p[e] = expf(a[e]-m);
    int e0=0;
    for (int e=1;e<NE;e++) if (p[e] > p[e0]) e0=e;          // ties -> first idx (matches top_k)
    int e1 = (e0==0)?1:0;
    for (int e=0;e<NE;e++) if (e!=e0 && p[e] > p[e1]) e1=e;
    float ss = p[e0]+p[e1];
    topw[t*2]   = p[e0]/ss;
    topw[t*2+1] = p[e1]/ss;
    int p0 = atomicAdd(&cnt[e0],1); bucket[e0*16384 + p0] = t*2;
    int p1 = atomicAdd(&cnt[e1],1); bucket[e1*16384 + p1] = t*2+1;
  }
}

__global__ void moe_prefix(const int* __restrict__ cnt, int* __restrict__ base){
  if (threadIdx.x==0 && blockIdx.x==0){
    int b=0; base[0]=0;
    for (int e=0;e<NE;e++){ b += cnt[e]; base[e+1]=b; }  // base[8] == 16384
    base[9] = base[8] + NTOK;
  }
}

// rows [0,16384): expert assignments (grouped); rows [16384,24576): shared (weight 1)
// inv[slot] = row, for the combine kernel
__global__ void moe_fill(const int* __restrict__ cnt, const int* __restrict__ base,
                         const int* __restrict__ bucket, const float* __restrict__ topw,
                         int* __restrict__ row_token, float* __restrict__ row_weight,
                         int* __restrict__ inv){
  int idx = blockIdx.x*blockDim.x + threadIdx.x;   // 544*256 = 8*16384 + 8192
  if (idx < NE*16384){
    int e = idx >> 14, p = idx & 16383;
    if (p < cnt[e]){
      int slot = bucket[idx];
      int row = base[e] + p;
      row_token[row]  = slot >> 1;
      row_weight[row] = topw[slot];
      inv[slot] = row;
    }
  } else {
    int t = idx - NE*16384;
    row_token[16384 + t]  = t;
    row_weight[16384 + t] = 1.0f;
  }
}

// ---------------- GEMM1: g = silu(Xg @ w1) * (Xg @ w3) ----------------
// T3+T4 deep pipeline: BK=32, 4-deep LDS ring, counted vmcnt (8 steady / 4 / 0 tail),
// raw s_barrier (ONE per K-tile, no drain), setprio around MFMA clusters.
// 512 thr = 8 waves (2M x 4N); BM=256, BN=128 (dual-B fits 128KB ring).
// Swizzle: row r, 16B-chunk slot p holds logical chunk p ^ ((r>>1)&3)  -> 2-way max (free).
// Safety: stage(t+3) targets buf[(t-1)&3] (reads done before barrier_t);
// vmcnt(8) at tile t is safe because tiles t+1,t+2 (8 loads) are issued strictly after tile t.
// XCD affinity: grid.x=24, xp=(x&7)*3+(x>>3) so XCD c owns 3 contiguous n-slices (B L2-resident).

#define BM1 256
#define BN1 128
#define NT1 64   // DIM/32

__global__ __launch_bounds__(512, 2) void moe_gemm1(
    const __hip_bfloat16* __restrict__ xb,    // [NTOK][DIM]
    const __hip_bfloat16* __restrict__ w1t,   // [9][HID_PAD][DIM]  (B^T)
    const __hip_bfloat16* __restrict__ w3t,
    const int* __restrict__ row_token,
    const int* __restrict__ base_,            // [10]
    __hip_bfloat16* __restrict__ g)           // [NROWS][HID_PAD]
{
  int e = blockIdx.z;
  int base = base_[e];
  int cnt  = base_[e+1] - base;
  int m0 = blockIdx.y * BM1;
  if (m0 >= cnt) return;
  int xp = (blockIdx.x & 7)*3 + (blockIdx.x >> 3);   // XCD-affine remap, bijective on [0,24)
  if (xp >= 22) return;
  int n0 = xp * BN1;

  __shared__ __align__(16) unsigned short lA [4][BM1][32];   // 64 KB ring
  __shared__ __align__(16) unsigned short lB1[4][BN1][32];   // 32 KB
  __shared__ __align__(16) unsigned short lB3[4][BN1][32];   // 32 KB
  __shared__ int tok[BM1];

  int tid = threadIdx.x;
  if (tid < BM1){
    int r = m0 + tid;
    tok[tid] = row_token[base + (r < cnt ? r : m0)];
  }
  __syncthreads();

  const __hip_bfloat16* w1e = w1t + (size_t)e*HID_PAD*DIM;
  const __hip_bfloat16* w3e = w3t + (size_t)e*HID_PAD*DIM;

  int wav = tid >> 6, lane = tid & 63;

  // staging sources: A = 1024 chunks (2/thread), B1/B3 = 512 chunks (1/thread)
  int c0 = tid,        r0c = c0 >> 2;
  int q0 = ((c0 & 3) ^ ((r0c >> 1) & 3)) * 8;
  int c1 = tid + 512,  r1c = c1 >> 2;
  int q1 = ((c1 & 3) ^ ((r1c >> 1) & 3)) * 8;
  const __hip_bfloat16* aS0 = xb  + (size_t)tok[r0c]*DIM + q0;
  const __hip_bfloat16* aS1 = xb  + (size_t)tok[r1c]*DIM + q1;
  const __hip_bfloat16* b1S = w1e + (size_t)(n0 + r0c)*DIM + q0;
  const __hip_bfloat16* b3S = w3e + (size_t)(n0 + r0c)*DIM + q0;

  int wm = (wav >> 2) * 128;           // 2 M-groups of 128
  int wn = (wav & 3) * 32;             // 4 N-groups of 32
  int lm = lane & 15, lq = lane >> 4;
  int sl = ((lq ^ ((lm >> 1) & 3)) << 3);   // read-side swizzled element offset

  v4f acc1[8][2], acc3[8][2];
  v4f vz = {0.f,0.f,0.f,0.f};
  #pragma unroll
  for (int i=0;i<8;i++)
    #pragma unroll
    for (int j=0;j<2;j++){ acc1[i][j]=vz; acc3[i][j]=vz; }

  // prologue: stage tiles 0,1,2 (12 loads/thread in flight)
  #pragma unroll
  for (int tt=0; tt<3; ++tt){
    int kk = tt*32;
    gload16(aS0 + kk, &lA [tt][0][0] + wav*512);
    gload16(aS1 + kk, &lA [tt][0][0] + wav*512 + 4096);
    gload16(b1S + kk, &lB1[tt][0][0] + wav*512);
    gload16(b3S + kk, &lB3[tt][0][0] + wav*512);
  }

  for (int t = 0; t < NT1; ++t){
    if (t < NT1-2)       asm volatile("s_waitcnt vmcnt(8)" ::: "memory");
    else if (t == NT1-2) asm volatile("s_waitcnt vmcnt(4)" ::: "memory");
    else                 asm volatile("s_waitcnt vmcnt(0)" ::: "memory");
    __builtin_amdgcn_s_barrier();
    asm volatile("" ::: "memory");     // keep ds_reads after the barrier

    int b = t & 3;
    v8bf b1f[2], b3f[2], af[4];
    #pragma unroll
    for (int j=0;j<2;j++){
      b1f[j] = *reinterpret_cast<const v8bf*>(&lB1[b][wn + j*16 + lm][sl]);
      b3f[j] = *reinterpret_cast<const v8bf*>(&lB3[b][wn + j*16 + lm][sl]);
    }
    #pragma unroll
    for (int i=0;i<4;i++)
      af[i] = *reinterpret_cast<const v8bf*>(&lA[b][wm + i*16 + lm][sl]);

    if (t + 3 < NT1){
      int kk = (t+3)*32, nb = (t+3) & 3;
      gload16(aS0 + kk, &lA [nb][0][0] + wav*512);
      gload16(aS1 + kk, &lA [nb][0][0] + wav*512 + 4096);
      gload16(b1S + kk, &lB1[nb][0][0] + wav*512);
      gload16(b3S + kk, &lB3[nb][0][0] + wav*512);
    }

    __builtin_amdgcn_s_setprio(1);
    #pragma unroll
    for (int i=0;i<4;i++)
      #pragma unroll
      for (int j=0;j<2;j++){
        acc1[i][j] = __builtin_amdgcn_mfma_f32_16x16x32_bf16(af[i], b1f[j], acc1[i][j], 0,0,0);
        acc3[i][j] = __builtin_amdgcn_mfma_f32_16x16x32_bf16(af[i], b3f[j], acc3[i][j], 0,0,0);
      }
    __builtin_amdgcn_s_setprio(0);

    #pragma unroll
    for (int i=0;i<4;i++)
      af[i] = *reinterpret_cast<const v8bf*>(&lA[b][wm + 64 + i*16 + lm][sl]);

    __builtin_amdgcn_s_setprio(1);
    #pragma unroll
    for (int i=0;i<4;i++)
      #pragma unroll
      for (int j=0;j<2;j++){
        acc1[4+i][j] = __builtin_amdgcn_mfma_f32_16x16x32_bf16(af[i], b1f[j], acc1[4+i][j], 0,0,0);
        acc3[4+i][j] = __builtin_amdgcn_mfma_f32_16x16x32_bf16(af[i], b3f[j], acc3[4+i][j], 0,0,0);
      }
    __builtin_amdgcn_s_setprio(0);
  }

  // epilogue: D layout col=lane&15, row=(lane>>4)*4+reg  [m89-verified]
  #pragma unroll
  for (int i=0;i<8;i++){
    #pragma unroll
    for (int r=0;r<4;r++){
      int ml = wm + i*16 + lq*4 + r;
      if (m0 + ml < cnt){
        size_t grow = (size_t)(base + m0 + ml) * HID_PAD;
        #pragma unroll
        for (int j=0;j<2;j++){
          float s1 = acc1[i][j][r];
          float s3 = acc3[i][j][r];
          float gv = (s1 / (1.0f + __expf(-s1))) * s3;   // silu(s1)*s3
          g[grow + n0 + wn + j*16 + lm] = __float2bfloat16(gv);
        }
      }
    }
  }
}

// ---------------- GEMM2: y[row] = weight * (g[row] @ w2) ----------------
// Same T3+T4 pipeline; BM=BN=256; grid.x = 8 => XCD = n-slice natively (w2 slice L2-resident).

#define BM2 256
#define BN2 256
#define NT2 88   // HID_PAD/32

__global__ __launch_bounds__(512, 2) void moe_gemm2(
    const __hip_bfloat16* __restrict__ g,     // [NROWS][HID_PAD]
    const __hip_bfloat16* __restrict__ w2t,   // [9][DIM][HID_PAD]  (B^T)
    const float* __restrict__ row_weight,
    const int* __restrict__ base_,
    float* __restrict__ y)                    // [NROWS][DIM] scratch (aliases w1t/w3t)
{
  int e = blockIdx.z;
  int base = base_[e];
  int cnt  = base_[e+1] - base;
  int m0 = blockIdx.y * BM2;
  if (m0 >= cnt) return;
  int n0 = blockIdx.x * BN2;

  __shared__ __align__(16) unsigned short lA[4][BM2][32];   // 64 KB ring
  __shared__ __align__(16) unsigned short lB[4][BN2][32];   // 64 KB ring
  __shared__ float wgt[BM2];

  int tid = threadIdx.x;
  if (tid < BM2){
    int r = m0 + tid;
    wgt[tid] = (r < cnt) ? row_weight[base + r] : 0.0f;
  }
  __syncthreads();

  const __hip_bfloat16* w2e = w2t + (size_t)e*DIM*HID_PAD;
  int wav = tid >> 6, lane = tid & 63;

  // A and B are both 1024 chunks: 2 loads/thread each
  int c0 = tid,        r0c = c0 >> 2;
  int q0 = ((c0 & 3) ^ ((r0c >> 1) & 3)) * 8;
  int c1 = tid + 512,  r1c = c1 >> 2;
  int q1 = ((c1 & 3) ^ ((r1c >> 1) & 3)) * 8;
  // A over-reach rows land in later valid rows of g; results discarded at store
  const __hip_bfloat16* aS0 = g   + (size_t)(base + m0 + r0c)*HID_PAD + q0;
  const __hip_bfloat16* aS1 = g   + (size_t)(base + m0 + r1c)*HID_PAD + q1;
  const __hip_bfloat16* bS0 = w2e + (size_t)(n0 + r0c)*HID_PAD + q0;
  const __hip_bfloat16* bS1 = w2e + (size_t)(n0 + r1c)*HID_PAD + q1;

  int wm = (wav >> 2) * 128;           // 2 M-groups of 128
  int wn = (wav & 3) * 64;             // 4 N-groups of 64
  int lm = lane & 15, lq = lane >> 4;
  int sl = ((lq ^ ((lm >> 1) & 3)) << 3);

  v4f acc[8][4];
  v4f vz = {0.f,0.f,0.f,0.f};
  #pragma unroll
  for (int i=0;i<8;i++)
    #pragma unroll
    for (int j=0;j<4;j++) acc[i][j]=vz;

  #pragma unroll
  for (int tt=0; tt<3; ++tt){
    int kk = tt*32;
    gload16(aS0 + kk, &lA[tt][0][0] + wav*512);
    gload16(aS1 + kk, &lA[tt][0][0] + wav*512 + 4096);
    gload16(bS0 + kk, &lB[tt][0][0] + wav*512);
    gload16(bS1 + kk, &lB[tt][0][0] + wav*512 + 4096);
  }

  for (int t = 0; t < NT2; ++t){
    if (t < NT2-2)       asm volatile("s_waitcnt vmcnt(8)" ::: "memory");
    else if (t == NT2-2) asm volatile("s_waitcnt vmcnt(4)" ::: "memory");
    else                 asm volatile("s_waitcnt vmcnt(0)" ::: "memory");
    __builtin_amdgcn_s_barrier();
    asm volatile("" ::: "memory");

    int b = t & 3;
    v8bf bf4[4], af[4];
    #pragma unroll
    for (int j=0;j<4;j++)
      bf4[j] = *reinterpret_cast<const v8bf*>(&lB[b][wn + j*16 + lm][sl]);
    #pragma unroll
    for (int i=0;i<4;i++)
      af[i] = *reinterpret_cast<const v8bf*>(&lA[b][wm + i*16 + lm][sl]);

    if (t + 3 < NT2){
      int kk = (t+3)*32, nb = (t+3) & 3;
      gload16(aS0 + kk, &lA[nb][0][0] + wav*512);
      gload16(aS1 + kk, &lA[nb][0][0] + wav*512 + 4096);
      gload16(bS0 + kk, &lB[nb][0][0] + wav*512);
      gload16(bS1 + kk, &lB[nb][0][0] + wav*512 + 4096);
    }

    __builtin_amdgcn_s_setprio(1);
    #pragma unroll
    for (int i=0;i<4;i++)
      #pragma unroll
      for (int j=0;j<4;j++)
        acc[i][j] = __builtin_amdgcn_mfma_f32_16x16x32_bf16(af[i], bf4[j], acc[i][j], 0,0,0);
    __builtin_amdgcn_s_setprio(0);

    #pragma unroll
    for (int i=0;i<4;i++)
      af[i] = *reinterpret_cast<const v8bf*>(&lA[b][wm + 64 + i*16 + lm][sl]);

    __builtin_amdgcn_s_setprio(1);
    #pragma unroll
    for (int i=0;i<4;i++)
      #pragma unroll
      for (int j=0;j<4;j++)
        acc[4+i][j] = __builtin_amdgcn_mfma_f32_16x16x32_bf16(af[i], bf4[j], acc[4+i][j], 0,0,0);
    __builtin_amdgcn_s_setprio(0);
  }

  #pragma unroll
  for (int i=0;i<8;i++){
    #pragma unroll
    for (int r=0;r<4;r++){
      int ml = wm + i*16 + lq*4 + r;
      if (m0 + ml < cnt){
        float wv = wgt[ml];
        size_t yrow = (size_t)(base + m0 + ml) * DIM;
        #pragma unroll
        for (int j=0;j<4;j++)
          y[yrow + n0 + wn + j*16 + lm] = wv * acc[i][j][r];
      }
    }
  }
}

// ---------------- combine: out[t] = y[shared_t] + y[r0] + y[r1] (y pre-weighted) ----------------

__global__ __launch_bounds__(256) void moe_combine(
    const float4* __restrict__ y, const int* __restrict__ inv, float4* __restrict__ out){
  int idx = blockIdx.x*blockDim.x + threadIdx.x;   // 8192 * 512
  int t = idx >> 9, d = idx & 511;
  float4 s = y[(((size_t)16384 + t) << 9) + d];
  int r0 = inv[t*2], r1 = inv[t*2+1];
  float4 a = y[((size_t)r0 << 9) + d];
  float4 b = y[((size_t)r1 << 9) + d];
  s.x += a.x + b.x; s.y += a.y + b.y; s.z += a.z + b.z; s.w += a.w + b.w;
  out[idx] = s;
}

// ---------------- host launch ----------------

extern "C" void kernel_launch(void* const* d_in, const int* in_sizes, int n_in,
                              void* d_out, int out_size, void* d_ws, size_t ws_size,
                              hipStream_t stream) {
  const float* x   = (const float*)d_in[0];
  const float* rw  = (const float*)d_in[1];
  const float* sw1 = (const float*)d_in[2];
  const float* sw2 = (const float*)d_in[3];
  const float* sw3 = (const float*)d_in[4];
  const float* ew1 = (const float*)d_in[5];
  const float* ew2 = (const float*)d_in[6];
  const float* ew3 = (const float*)d_in[7];
  float* out = (float*)d_out;

  char* ws = (char*)d_ws;
  size_t off = 0;
  auto nxt = [&](size_t b) -> char* {
    char* p = ws + off; off += (b + 255) & ~(size_t)255; return p;
  };
  __hip_bfloat16* xb  = (__hip_bfloat16*)nxt((size_t)NTOK*DIM*2);          // 33.5 MB
  __hip_bfloat16* w1t = (__hip_bfloat16*)nxt((size_t)9*HID_PAD*DIM*2);     // 103.8 MB
  __hip_bfloat16* w3t = (__hip_bfloat16*)nxt((size_t)9*HID_PAD*DIM*2);     // 103.8 MB
  __hip_bfloat16* w2t = (__hip_bfloat16*)nxt((size_t)9*DIM*HID_PAD*2);     // 103.8 MB
  __hip_bfloat16* g   = (__hip_bfloat16*)nxt((size_t)NROWS*HID_PAD*2);     // 138.4 MB
  float* topw      = (float*)nxt(16384*4);
  int*   cnt       = (int*)  nxt(32);
  int*   base_     = (int*)  nxt(64);
  int*   bucket    = (int*)  nxt(NE*16384*4);
  int*   row_token = (int*)  nxt(NROWS*4);
  float* row_weight= (float*)nxt(NROWS*4);
  int*   inv       = (int*)  nxt(16384*4);

  // y scratch (201.3 MB fp32) aliases w1t+w3t (207.6 MB) — dead after gemm1,
  // written by gemm2, read by combine; stream-ordered so no hazard.
  static_assert((size_t)NROWS*DIM*4 <= 2*((size_t)9*HID_PAD*DIM*2), "y alias overflow");
  float* y = (float*)w1t;

  if (off > ws_size) {
    fprintf(stderr, "MoE kernel: ws too small (%zu needed, %zu given)\n", off, ws_size);
    return;
  }

  moe_zero_i<<<1, 32, 0, stream>>>(cnt, NE);
  moe_cast_x<<<16384, 256, 0, stream>>>(x, xb);

  dim3 tb(32,8);
  moe_tcast<<<dim3(88,64,9), tb, 0, stream>>>(ew1, sw1, w1t, DIM, HID, HID_PAD, DIM);
  moe_tcast<<<dim3(88,64,9), tb, 0, stream>>>(ew3, sw3, w3t, DIM, HID, HID_PAD, DIM);
  moe_tcast<<<dim3(64,88,9), tb, 0, stream>>>(ew2, sw2, w2t, HID, DIM, DIM, HID_PAD);

  moe_router<<<NTOK/4, 256, 0, stream>>>(x, rw, topw, cnt, bucket);
  moe_prefix<<<1, 1, 0, stream>>>(cnt, base_);
  moe_fill<<<544, 256, 0, stream>>>(cnt, base_, bucket, topw, row_token, row_weight, inv);

  // max cnt per group is 8192 -> 32 M-blocks of 256 suffice
  moe_gemm1<<<dim3(24,32,9), 512, 0, stream>>>(xb, w1t, w3t, row_token, base_, g);
  moe_gemm2<<<dim3(8,32,9), 512, 0, stream>>>(g, w2t, row_weight, base_, y);
  moe_combine<<<16384, 256, 0, stream>>>((const float4*)y, inv, (float4*)out);
}